// Round 2
// baseline (1893.412 us; speedup 1.0000x reference)
//
#include <hip/hip_runtime.h>
#include <hip/hip_bf16.h>
#include <math.h>

#define B_  64
#define T_  32
#define E_  512
#define D_  512
#define V_  32000
#define NT  31            // T-1 decode steps
#define G4  2048          // 4*D
#define NBLK 256          // k_lstm grid: 1 block/CU, all co-resident

typedef __attribute__((ext_vector_type(8))) short short8;
typedef __attribute__((ext_vector_type(4))) float f32x4;
typedef __hip_bfloat16 bf16;

__device__ __forceinline__ float sigmoidf_(float x) { return 1.f / (1.f + expf(-x)); }
// gate-interleaved permutation: col n = d*4+gate  <->  original row gate*512+d
__device__ __forceinline__ int perm_(int n) { return ((n & 3) << 9) + (n >> 2); }

// ---------------- kernel 1: stable descending argsort + init ----------------
__global__ void k_sort(const int* __restrict__ caplen, float* __restrict__ out_sind,
                       int* __restrict__ sind, int* __restrict__ declen,
                       int* __restrict__ Mact, int* __restrict__ rowlist,
                       float* __restrict__ h0, float* __restrict__ c0,
                       int* __restrict__ slots, int* __restrict__ genp) {
    __shared__ int s_len[B_];
    __shared__ int s_dl[B_];
    int tid = threadIdx.x;
    if (tid < B_) s_len[tid] = caplen[tid];
    __syncthreads();
    if (tid < B_) {
        int len = s_len[tid];
        int rank = 0;
        for (int j = 0; j < B_; ++j) {
            int lj = s_len[j];
            rank += (lj > len) || (lj == len && j < tid);   // stable: ties by index
        }
        sind[rank] = tid;
        declen[rank] = len - 1;
        s_dl[rank] = len - 1;
        out_sind[rank] = (float)tid;
    }
    __syncthreads();
    if (tid == 0) {
        int base = 0;
        for (int t = 0; t < NT; ++t) {
            int n = 0;
            for (int b = 0; b < B_; ++b) n += (t < s_dl[b]);
            for (int b = 0; b < n; ++b) rowlist[base + b] = t * B_ + b;
            base += n;
        }
        Mact[0] = base;
        genp[0] = 0;
    }
    for (int i = tid; i < NBLK * 32; i += blockDim.x) slots[i] = 0;   // barrier flags
    for (int i = tid; i < B_ * D_; i += blockDim.x) { h0[i] = 0.f; c0[i] = 0.f; }
}

// ---------------- kernel 2: zero-fill predictions ----------------
__global__ void k_zero(float4* __restrict__ out, int n4) {
    int i = blockIdx.x * blockDim.x + threadIdx.x;
    int stride = gridDim.x * blockDim.x;
    float4 z = make_float4(0.f, 0.f, 0.f, 0.f);
    for (; i < n4; i += stride) out[i] = z;
}

// ---------------- kernel 3: fc_w -> bf16 ----------------
__global__ void k_cvt_fcw(const float4* __restrict__ fcw, ushort4* __restrict__ fcwb, int n4) {
    int i = blockIdx.x * blockDim.x + threadIdx.x;
    int stride = gridDim.x * blockDim.x;
    for (; i < n4; i += stride) {
        float4 v = fcw[i];
        bf16 a = __float2bfloat16(v.x), b = __float2bfloat16(v.y);
        bf16 c = __float2bfloat16(v.z), d = __float2bfloat16(v.w);
        ushort4 o;
        o.x = *(unsigned short*)&a; o.y = *(unsigned short*)&b;
        o.z = *(unsigned short*)&c; o.w = *(unsigned short*)&d;
        fcwb[i] = o;
    }
}

// ---------------- kernel 4: X = enc_sorted @ Wih[perm].T + bias[perm] (fp32) ----------------
__global__ __launch_bounds__(256) void k_xgemm(
    const float* __restrict__ enc, const float* __restrict__ Wih,
    const float* __restrict__ bih, const float* __restrict__ bhh,
    const int* __restrict__ sind, float* __restrict__ X) {
    __shared__ __align__(16) float sA[16 * 68];
    __shared__ __align__(16) float sB[16 * 68];
    __shared__ int s_sind[B_];
    int tid = threadIdx.x;
    int mt = blockIdx.x;
    int n0 = blockIdx.y * 64;
    if (tid < B_) s_sind[tid] = sind[tid];
    __syncthreads();
    int la = tid >> 2;
    int lk = (tid & 3) << 2;
    int tx = tid & 15, ty = tid >> 4;
    const float* arow = enc + ((long)s_sind[la] * T_ + mt) * E_;
    const float* brow = Wih + (long)perm_(n0 + la) * E_;
    float acc[4][4] = {};
    for (int k0 = 0; k0 < E_; k0 += 16) {
        float4 a4 = *(const float4*)(arow + k0 + lk);
        float4 b4 = *(const float4*)(brow + k0 + lk);
        sA[(lk + 0) * 68 + la] = a4.x; sA[(lk + 1) * 68 + la] = a4.y;
        sA[(lk + 2) * 68 + la] = a4.z; sA[(lk + 3) * 68 + la] = a4.w;
        sB[(lk + 0) * 68 + la] = b4.x; sB[(lk + 1) * 68 + la] = b4.y;
        sB[(lk + 2) * 68 + la] = b4.z; sB[(lk + 3) * 68 + la] = b4.w;
        __syncthreads();
        #pragma unroll
        for (int kk = 0; kk < 16; ++kk) {
            float4 av = *(const float4*)&sA[kk * 68 + (ty << 2)];
            float4 bv = *(const float4*)&sB[kk * 68 + (tx << 2)];
            float a[4] = { av.x, av.y, av.z, av.w };
            float b[4] = { bv.x, bv.y, bv.z, bv.w };
            #pragma unroll
            for (int i = 0; i < 4; ++i)
                #pragma unroll
                for (int j = 0; j < 4; ++j)
                    acc[i][j] = fmaf(a[i], b[j], acc[i][j]);
        }
        __syncthreads();
    }
    #pragma unroll
    for (int i = 0; i < 4; ++i) {
        int b = (ty << 2) + i;
        int row = mt * 64 + b;
        int col0 = n0 + (tx << 2);
        float* xp = X + (long)row * G4 + col0;
        #pragma unroll
        for (int j = 0; j < 4; ++j) {
            int pc = perm_(col0 + j);
            xp[j] = acc[i][j] + bih[pc] + bhh[pc];
        }
    }
}

// ---------------- kernel 5: persistent fused LSTM — all 31 steps, one launch ----------------
// 256 blocks x 512 thr (1 block/CU, 8 waves). Block owns 8 gate-cols (= 2 d's x 4 gates).
// W staged in LDS ONCE; c + inactive-h carry in registers. Hand-rolled grid barrier
// (agent-scope release/acquire atomics in workspace) replaces 31 kernel launches.
// Co-residency: 8 waves + 19KB LDS -> >=4 blocks/CU capacity, grid = 1 block/CU. Safe.
__global__ __launch_bounds__(512) void k_lstm(
    const float* __restrict__ X, const float* __restrict__ Whh,
    float* __restrict__ hb0, float* __restrict__ hb1,
    bf16* __restrict__ hstoreb, const int* __restrict__ declen,
    int* __restrict__ slots, int* __restrict__ genp) {
    __shared__ __align__(16) float sW[8][520];   // padded: 520%32=8 -> tx spreads banks
    __shared__ float sg[8][65];
    __shared__ int sdl[B_];
    int tid = threadIdx.x;
    int bid = blockIdx.x;
    int n0 = bid * 8;
    if (tid < B_) sdl[tid] = declen[tid];
    // stage W once: 8 cols x 512 k, original Whh rows via perm (row-major, k contiguous)
    {
        int ci = tid >> 6;            // 0..7
        int kb = (tid & 63) << 3;     // 0,8,...,504
        const float* wr = Whh + (long)perm_(n0 + ci) * D_ + kb;
        float4 w0 = *(const float4*)(wr + 0);
        float4 w1 = *(const float4*)(wr + 4);
        *(float4*)&sW[ci][kb + 0] = w0;
        *(float4*)&sW[ci][kb + 4] = w1;
    }
    __syncthreads();
    int tx = tid & 7;
    int ty = tid >> 3;                // 0..63 : one batch-row per thread
    int n = n0 + tx;
    int g = tx & 3;
    // c-update ownership: tid<128 -> (b = tid&63, dl = tid>>6), d = bid*2+dl
    int cb = tid & 63, cdl = (tid >> 6) & 1;
    int cd = bid * 2 + cdl;
    int cidx = cb * D_ + cd;
    float creg = 0.f;                 // c state in registers across all steps
    float hreg = 0.f;                 // h carry (covers inactive rows) in registers

    for (int t = 0; t < NT; ++t) {
        const float* hold = (t & 1) ? hb1 : hb0;
        float*       hnew = (t & 1) ? hb0 : hb1;
        float xv = X[(t * B_ + ty) * G4 + n];   // issued early, consumed after FMA loop
        const float* hA = hold + ty * D_;
        float acc0 = 0.f, acc1 = 0.f;           // split-K: two independent dep chains
        #pragma unroll 8
        for (int k = 0; k < 256; k += 4) {
            float4 w4 = *(const float4*)&sW[tx][k];
            float4 u4 = *(const float4*)&sW[tx][k + 256];
            float4 a4 = *(const float4*)(hA + k);
            float4 b4 = *(const float4*)(hA + k + 256);
            acc0 = fmaf(a4.x, w4.x, acc0); acc0 = fmaf(a4.y, w4.y, acc0);
            acc0 = fmaf(a4.z, w4.z, acc0); acc0 = fmaf(a4.w, w4.w, acc0);
            acc1 = fmaf(b4.x, u4.x, acc1); acc1 = fmaf(b4.y, u4.y, acc1);
            acc1 = fmaf(b4.z, u4.z, acc1); acc1 = fmaf(b4.w, u4.w, acc1);
        }
        float p0 = (acc0 + acc1) + xv;
        sg[tx][ty] = (g == 2) ? tanhf(p0) : sigmoidf_(p0);
        __syncthreads();
        if (tid < 128) {
            float gi = sg[cdl * 4 + 0][cb];
            float gf = sg[cdl * 4 + 1][cb];
            float gg = sg[cdl * 4 + 2][cb];
            float go = sg[cdl * 4 + 3][cb];
            float cn = gf * creg + gi * gg;
            float hn = go * tanhf(cn);
            hstoreb[(t * B_ + cb) * D_ + cd] = __float2bfloat16(hn);
            if (t < sdl[cb]) { creg = cn; hreg = hn; }
            hnew[cidx] = hreg;
        }
        if (t == NT - 1) break;                 // no barrier needed after last step
        // ---- grid barrier (flag + generation, agent scope) ----
        __syncthreads();                        // drains all threads' stores (vmcnt 0)
        if (tid == 0)
            __hip_atomic_store(&slots[bid * 32], t + 1, __ATOMIC_RELEASE,
                               __HIP_MEMORY_SCOPE_AGENT);
        if (bid == 0) {
            if (tid < NBLK) {
                while (__hip_atomic_load(&slots[tid * 32], __ATOMIC_ACQUIRE,
                                         __HIP_MEMORY_SCOPE_AGENT) < t + 1)
                    __builtin_amdgcn_s_sleep(1);
            }
            __syncthreads();
            if (tid == 0)
                __hip_atomic_store(genp, t + 1, __ATOMIC_RELEASE,
                                   __HIP_MEMORY_SCOPE_AGENT);
        } else {
            if (tid == 0) {
                while (__hip_atomic_load(genp, __ATOMIC_ACQUIRE,
                                         __HIP_MEMORY_SCOPE_AGENT) < t + 1)
                    __builtin_amdgcn_s_sleep(1);
            }
            __syncthreads();
        }
    }
}

// ---------------- kernel 6: preds = hstore_b[active] @ fcw_b.T + fc_b (MFMA bf16) ----------------
__global__ __launch_bounds__(256) void k_fc(
    const bf16* __restrict__ hstoreb, const bf16* __restrict__ fcwb,
    const float* __restrict__ fcb, const int* __restrict__ rowlist,
    const int* __restrict__ Mact, float* __restrict__ out) {
    __shared__ int srow[128];
    int tid = threadIdx.x, lane = tid & 63, w = tid >> 6;
    int mt = blockIdx.x, nb = blockIdx.y;
    int Ma = Mact[0];
    if (mt * 128 >= Ma) return;           // uniform early-exit (zero-fill already done)
    if (tid < 128) {
        int r = mt * 128 + tid;
        srow[tid] = (r < Ma) ? rowlist[r] : -1;
    }
    __syncthreads();
    int m0w = (w & 1) * 64;
    int n0w = (w >> 1) * 64;
    int koff = (lane >> 4) << 3;
    const bf16* aptr[4];
    const bf16* bptr[4];
    #pragma unroll
    for (int ms = 0; ms < 4; ++ms) {
        int rv = srow[m0w + ms * 16 + (lane & 15)];
        aptr[ms] = hstoreb + (long)(rv < 0 ? 0 : rv) * D_ + koff;
    }
    #pragma unroll
    for (int ns = 0; ns < 4; ++ns) {
        int n = nb * 128 + n0w + ns * 16 + (lane & 15);
        bptr[ns] = fcwb + (long)n * D_ + koff;
    }
    f32x4 acc[4][4] = {};
    for (int kc = 0; kc < D_; kc += 32) {
        short8 a[4], b[4];
        #pragma unroll
        for (int ms = 0; ms < 4; ++ms) a[ms] = *(const short8*)(aptr[ms] + kc);
        #pragma unroll
        for (int ns = 0; ns < 4; ++ns) b[ns] = *(const short8*)(bptr[ns] + kc);
        #pragma unroll
        for (int ms = 0; ms < 4; ++ms)
            #pragma unroll
            for (int ns = 0; ns < 4; ++ns)
                acc[ms][ns] = __builtin_amdgcn_mfma_f32_16x16x32_bf16(a[ms], b[ns], acc[ms][ns], 0, 0, 0);
    }
    #pragma unroll
    for (int ms = 0; ms < 4; ++ms) {
        #pragma unroll
        for (int r = 0; r < 4; ++r) {
            int rloc = m0w + ms * 16 + ((lane >> 4) << 2) + r;
            int rv = srow[rloc];
            if (rv < 0) continue;
            int tt = rv >> 6, b = rv & 63;
            #pragma unroll
            for (int ns = 0; ns < 4; ++ns) {
                int n = nb * 128 + n0w + ns * 16 + (lane & 15);
                out[((long)(b * NT + tt)) * V_ + n] = acc[ms][ns][r] + fcb[n];
            }
        }
    }
}

extern "C" void kernel_launch(void* const* d_in, const int* in_sizes, int n_in,
                              void* d_out, int out_size, void* d_ws, size_t ws_size,
                              hipStream_t stream) {
    const float* enc    = (const float*)d_in[0];
    const int*   caplen = (const int*)d_in[1];
    const float* Wih    = (const float*)d_in[2];
    const float* Whh    = (const float*)d_in[3];
    const float* bih    = (const float*)d_in[4];
    const float* bhh    = (const float*)d_in[5];
    const float* fcw    = (const float*)d_in[6];
    const float* fcb    = (const float*)d_in[7];
    float* out = (float*)d_out;

    // workspace carve (~51.6 MB)
    char* ws = (char*)d_ws;
    int* sind    = (int*)ws;                          // 64
    int* declen  = sind + 64;                         // 64
    int* Mact    = declen + 64;                       // 64 (padded)
    int* rowlist = Mact + 64;                         // 2048
    int* genp    = rowlist + 2048;                    // 64 (own line)
    int* slots   = genp + 64;                         // 256*32 ints (128B stride/block)
    char* p = (char*)(slots + NBLK * 32);
    p = (char*)(((size_t)p + 255) & ~(size_t)255);
    float* X      = (float*)p;            p += (size_t)NT * B_ * G4 * 4;   // 16.25 MB
    float* c      = (float*)p;            p += (size_t)B_ * D_ * 4;        // 128 KB (unused)
    float* h0     = (float*)p;            p += (size_t)B_ * D_ * 4;
    float* h1     = (float*)p;            p += (size_t)B_ * D_ * 4;
    bf16* hstoreb = (bf16*)p;             p += (size_t)NT * B_ * D_ * 2;   // 2 MB
    bf16* fcwb    = (bf16*)p;             p += (size_t)V_ * D_ * 2;        // 32.8 MB

    float* out_sind = out + (long)B_ * NT * V_;

    k_sort<<<1, 256, 0, stream>>>(caplen, out_sind, sind, declen, Mact, rowlist, h0, c,
                                  slots, genp);
    k_zero<<<4096, 256, 0, stream>>>((float4*)out, (B_ * NT * V_) / 4);
    k_cvt_fcw<<<4096, 256, 0, stream>>>((const float4*)fcw, (ushort4*)fcwb, (V_ * D_) / 4);
    k_xgemm<<<dim3(NT, G4 / 64), 256, 0, stream>>>(enc, Wih, bih, bhh, sind, X);
    k_lstm<<<NBLK, 512, 0, stream>>>(X, Whh, h0, h1, hstoreb, declen, slots, genp);
    k_fc<<<dim3(16, V_ / 128), 256, 0, stream>>>(hstoreb, fcwb, fcb, rowlist, Mact, out);
}

// Round 3
// 878.074 us; speedup vs baseline: 2.1563x; 2.1563x over previous
//
#include <hip/hip_runtime.h>
#include <hip/hip_bf16.h>
#include <math.h>

#define B_  64
#define T_  32
#define E_  512
#define D_  512
#define V_  32000
#define NT  31            // T-1 decode steps
#define G4  2048          // 4*D
#define NBLK 256          // k_lstm grid: 1 block/CU, all co-resident

typedef __attribute__((ext_vector_type(8))) short short8;
typedef __attribute__((ext_vector_type(4))) float f32x4;
typedef __hip_bfloat16 bf16;

__device__ __forceinline__ float sigmoidf_(float x) { return 1.f / (1.f + expf(-x)); }
// gate-interleaved permutation: col n = d*4+gate  <->  original row gate*512+d
__device__ __forceinline__ int perm_(int n) { return ((n & 3) << 9) + (n >> 2); }

// ---------------- kernel 1: stable descending argsort + init ----------------
__global__ void k_sort(const int* __restrict__ caplen, float* __restrict__ out_sind,
                       int* __restrict__ sind, int* __restrict__ declen,
                       int* __restrict__ Mact, int* __restrict__ rowlist,
                       float4* __restrict__ hz, int* __restrict__ cntp) {
    __shared__ int s_len[B_];
    __shared__ int s_dl[B_];
    __shared__ int s_cnt[NT];
    __shared__ int s_pre[NT + 1];
    int tid = threadIdx.x;
    if (tid < B_) s_len[tid] = caplen[tid];
    __syncthreads();
    if (tid < B_) {
        int len = s_len[tid];
        int rank = 0;
        for (int j = 0; j < B_; ++j) {
            int lj = s_len[j];
            rank += (lj > len) || (lj == len && j < tid);   // stable: ties by index
        }
        sind[rank] = tid;
        declen[rank] = len - 1;
        s_dl[rank] = len - 1;
        out_sind[rank] = (float)tid;
    }
    __syncthreads();
    if (tid < NT) {
        int cnt = 0;
        for (int b = 0; b < B_; ++b) cnt += (tid < s_dl[b]);
        s_cnt[tid] = cnt;
    }
    __syncthreads();
    if (tid == 0) {
        int acc = 0;
        for (int t = 0; t < NT; ++t) { s_pre[t] = acc; acc += s_cnt[t]; }
        s_pre[NT] = acc;
        Mact[0] = acc;
        cntp[0] = 0;                       // grid-barrier counter (fresh each replay)
    }
    __syncthreads();
    int Ma = s_pre[NT];
    // full rowlist: [0,Ma) active rows (same order as before), [Ma,1984) inactive|flag
    for (int i = tid; i < NT * B_; i += blockDim.x) {
        int t = i >> 6, b = i & 63;
        bool act = (t < s_dl[b]);          // declen descending -> active iff b < cnt_t
        int pos = act ? (s_pre[t] + b)
                      : (Ma + (t * B_ - s_pre[t]) + (b - s_cnt[t]));
        rowlist[pos] = (t * B_ + b) | (act ? 0 : (1 << 30));
    }
    // zero h0 and h1 (contiguous) as float4
    for (int i = tid; i < (2 * B_ * D_) / 4; i += blockDim.x)
        hz[i] = make_float4(0.f, 0.f, 0.f, 0.f);
}

// ---------------- kernel 2: fc_w -> bf16 ----------------
__global__ void k_cvt_fcw(const float4* __restrict__ fcw, ushort4* __restrict__ fcwb, int n4) {
    int i = blockIdx.x * blockDim.x + threadIdx.x;
    int stride = gridDim.x * blockDim.x;
    for (; i < n4; i += stride) {
        float4 v = fcw[i];
        bf16 a = __float2bfloat16(v.x), b = __float2bfloat16(v.y);
        bf16 c = __float2bfloat16(v.z), d = __float2bfloat16(v.w);
        ushort4 o;
        o.x = *(unsigned short*)&a; o.y = *(unsigned short*)&b;
        o.z = *(unsigned short*)&c; o.w = *(unsigned short*)&d;
        fcwb[i] = o;
    }
}

// ---------------- kernel 3: X = enc_sorted @ Wih[perm].T + bias[perm] (fp32) ----------------
__global__ __launch_bounds__(256) void k_xgemm(
    const float* __restrict__ enc, const float* __restrict__ Wih,
    const float* __restrict__ bih, const float* __restrict__ bhh,
    const int* __restrict__ sind, float* __restrict__ X) {
    __shared__ __align__(16) float sA[16 * 68];
    __shared__ __align__(16) float sB[16 * 68];
    __shared__ int s_sind[B_];
    int tid = threadIdx.x;
    int mt = blockIdx.x;
    int n0 = blockIdx.y * 64;
    if (tid < B_) s_sind[tid] = sind[tid];
    __syncthreads();
    int la = tid >> 2;
    int lk = (tid & 3) << 2;
    int tx = tid & 15, ty = tid >> 4;
    const float* arow = enc + ((long)s_sind[la] * T_ + mt) * E_;
    const float* brow = Wih + (long)perm_(n0 + la) * E_;
    float acc[4][4] = {};
    for (int k0 = 0; k0 < E_; k0 += 16) {
        float4 a4 = *(const float4*)(arow + k0 + lk);
        float4 b4 = *(const float4*)(brow + k0 + lk);
        sA[(lk + 0) * 68 + la] = a4.x; sA[(lk + 1) * 68 + la] = a4.y;
        sA[(lk + 2) * 68 + la] = a4.z; sA[(lk + 3) * 68 + la] = a4.w;
        sB[(lk + 0) * 68 + la] = b4.x; sB[(lk + 1) * 68 + la] = b4.y;
        sB[(lk + 2) * 68 + la] = b4.z; sB[(lk + 3) * 68 + la] = b4.w;
        __syncthreads();
        #pragma unroll
        for (int kk = 0; kk < 16; ++kk) {
            float4 av = *(const float4*)&sA[kk * 68 + (ty << 2)];
            float4 bv = *(const float4*)&sB[kk * 68 + (tx << 2)];
            float a[4] = { av.x, av.y, av.z, av.w };
            float b[4] = { bv.x, bv.y, bv.z, bv.w };
            #pragma unroll
            for (int i = 0; i < 4; ++i)
                #pragma unroll
                for (int j = 0; j < 4; ++j)
                    acc[i][j] = fmaf(a[i], b[j], acc[i][j]);
        }
        __syncthreads();
    }
    #pragma unroll
    for (int i = 0; i < 4; ++i) {
        int b = (ty << 2) + i;
        int row = mt * 64 + b;
        int col0 = n0 + (tx << 2);
        float* xp = X + (long)row * G4 + col0;
        #pragma unroll
        for (int j = 0; j < 4; ++j) {
            int pc = perm_(col0 + j);
            xp[j] = acc[i][j] + bih[pc] + bhh[pc];
        }
    }
}

// ---------------- kernel 4: persistent fused LSTM — all 31 steps, one launch ----------------
// 256 blocks x 512 thr (co-resident: 8 waves, 37KB LDS, ~130 VGPR -> >=2 blocks/CU cap).
// Block owns 8 gate-cols. W in LDS once. c + inactive-h carry in registers.
// Cross-block h via L3 only: writes = relaxed agent atomics (sc1), reads = asm sc0sc1
// dwordx4 (bypass L1/L2). Grid barrier = single relaxed atomic counter. NO acquire/
// release anywhere -> no buffer_inv/wbl2 (the round-2 40us/step killer); L2 stays warm
// for X and Whh. h reads: lane tx takes float4s (tx+8*kk) of row ty -> each instruction
// covers 128B contiguous per 8-lane group (full-line coalescing despite no-allocate).
__global__ __launch_bounds__(512) void k_lstm(
    const float* __restrict__ X, const float* __restrict__ Whh,
    float* __restrict__ hb0, float* __restrict__ hb1,
    bf16* __restrict__ hstoreb, const int* __restrict__ declen,
    int* __restrict__ cnt) {
    __shared__ __align__(16) float sW[8][520];     // [col][k], pad 520: bank-safe
    __shared__ __align__(16) float sp[64 * 72];    // partials [ty][q*8+col], stride 72
    __shared__ float sg[8][65];
    __shared__ int sdl[B_];
    int tid = threadIdx.x;
    int bid = blockIdx.x;
    int n0 = bid * 8;
    if (tid < B_) sdl[tid] = declen[tid];
    {   // stage W once: 8 cols x 512 k (original Whh rows via perm, k contiguous)
        int ci = tid >> 6;            // 0..7
        int kb = (tid & 63) << 3;     // 0,8,...,504
        const float* wr = Whh + (long)perm_(n0 + ci) * D_ + kb;
        float4 w0 = *(const float4*)(wr + 0);
        float4 w1 = *(const float4*)(wr + 4);
        *(float4*)&sW[ci][kb + 0] = w0;
        *(float4*)&sW[ci][kb + 4] = w1;
    }
    __syncthreads();
    int tx = tid & 7;                 // k-chunk lane (also: col in reduce phase)
    int ty = tid >> 3;                // 0..63 batch row
    // c-update ownership: tid<128 -> (b = tid&63, dl = tid>>6), d = bid*2+dl
    int cb = tid & 63, cdl = (tid >> 6) & 1;
    int cd = bid * 2 + cdl;
    int cidx = cb * D_ + cd;
    float creg = 0.f;                 // c state in registers across all steps
    float hreg = 0.f;                 // h carry (covers inactive rows) in registers

    for (int t = 0; t < NT; ++t) {
        const float* hold = (t & 1) ? hb1 : hb0;
        float*       hnew = (t & 1) ? hb0 : hb1;
        // ---- phase A: coherent h loads (L3) + partial dot over this lane's k-chunk
        const float* hrow = hold + ty * D_;
        float4 hv[16];
        #pragma unroll
        for (int kk = 0; kk < 16; ++kk) {
            const float* ap = hrow + ((tx + (kk << 3)) << 2);
            asm volatile("global_load_dwordx4 %0, %1, off sc0 sc1"
                         : "=v"(hv[kk]) : "v"(ap));
        }
        float xv = X[(t * B_ + ty) * G4 + (n0 + tx)];     // L2-warm, used in phase C
        asm volatile("s_waitcnt vmcnt(0)" ::: "memory");
        __builtin_amdgcn_sched_barrier(0);
        float p[8] = {};
        #pragma unroll
        for (int kk = 0; kk < 16; ++kk) {
            int k = (tx + (kk << 3)) << 2;
            #pragma unroll
            for (int j = 0; j < 8; ++j) {
                float4 w4 = *(const float4*)&sW[j][k];   // banks 4*tx..: conflict-free
                p[j] = fmaf(hv[kk].x, w4.x, p[j]);
                p[j] = fmaf(hv[kk].y, w4.y, p[j]);
                p[j] = fmaf(hv[kk].z, w4.z, p[j]);
                p[j] = fmaf(hv[kk].w, w4.w, p[j]);
            }
        }
        float* spp = &sp[ty * 72 + tx * 8];
        *(float4*)(spp + 0) = make_float4(p[0], p[1], p[2], p[3]);
        *(float4*)(spp + 4) = make_float4(p[4], p[5], p[6], p[7]);
        __syncthreads();
        // ---- phase C: reduce 8 partials + bias'd X, activation. thread(tx,ty)->col tx
        {
            float s = xv;
            #pragma unroll
            for (int q = 0; q < 8; ++q) s += sp[ty * 72 + q * 8 + tx];
            sg[tx][ty] = ((tx & 3) == 2) ? tanhf(s) : sigmoidf_(s);
        }
        __syncthreads();
        // ---- phase D: c/h update, h store (coherent, L3)
        if (tid < 128) {
            float gi = sg[cdl * 4 + 0][cb];
            float gf = sg[cdl * 4 + 1][cb];
            float gg = sg[cdl * 4 + 2][cb];
            float go = sg[cdl * 4 + 3][cb];
            float cn = gf * creg + gi * gg;
            float hn = go * tanhf(cn);
            hstoreb[(t * B_ + cb) * D_ + cd] = __float2bfloat16(hn);
            if (t < sdl[cb]) { creg = cn; hreg = hn; }
            __hip_atomic_store((unsigned*)(hnew + cidx), __float_as_uint(hreg),
                               __ATOMIC_RELAXED, __HIP_MEMORY_SCOPE_AGENT);
        }
        if (t == NT - 1) break;                 // no barrier needed after last step
        // ---- grid barrier: single relaxed counter (sc1 atomics only, no cache ops)
        __syncthreads();                        // drains vmcnt -> h stores visible in L3
        if (tid == 0) {
            __hip_atomic_fetch_add(cnt, 1, __ATOMIC_RELAXED, __HIP_MEMORY_SCOPE_AGENT);
            int target = (t + 1) * NBLK;
            while (__hip_atomic_load(cnt, __ATOMIC_RELAXED,
                                     __HIP_MEMORY_SCOPE_AGENT) < target)
                __builtin_amdgcn_s_sleep(1);
        }
        __syncthreads();
    }
}

// ---------------- kernel 5: preds = hstore_b @ fcw_b.T + fc_b (MFMA bf16) ----------------
// Covers ALL 1984 (b,t) rows: active -> GEMM result, inactive -> exact 0 (k_zero fused).
// XCD-locality remap: the 16 mt-blocks sharing one fcwb tile land on one XCD's L2.
__global__ __launch_bounds__(256) void k_fc(
    const bf16* __restrict__ hstoreb, const bf16* __restrict__ fcwb,
    const float* __restrict__ fcb, const int* __restrict__ rowlist,
    const int* __restrict__ Mact, float* __restrict__ out) {
    __shared__ int srow[128];
    int tid = threadIdx.x, lane = tid & 63, w = tid >> 6;
    int flat = blockIdx.x + (blockIdx.y << 4);   // grid (16,256) = 4096 slots
    int g = flat & 7, s = flat >> 3;             // XCD (round-robin), slot on XCD
    int nb = g + ((s >> 4) << 3);                // nb = g + 8q: 16 consecutive slots/nb
    int mt = s & 15;
    if (nb >= V_ / 128) return;                  // 250 nb values; 96 idle blocks
    int Ma = Mact[0];
    if (tid < 128) {
        int r = mt * 128 + tid;
        srow[tid] = (r < B_ * NT) ? rowlist[r] : -1;
    }
    __syncthreads();
    int m0w = (w & 1) * 64;
    int n0w = (w >> 1) * 64;
    int koff = (lane >> 4) << 3;
    f32x4 acc[4][4] = {};
    bool compute = (mt * 128 < Ma);              // actives are first in rowlist
    if (compute) {
        const bf16* aptr[4];
        const bf16* bptr[4];
        #pragma unroll
        for (int ms = 0; ms < 4; ++ms) {
            int rv = srow[m0w + ms * 16 + (lane & 15)];
            aptr[ms] = hstoreb + (long)(rv < 0 ? 0 : (rv & 2047)) * D_ + koff;
        }
        #pragma unroll
        for (int ns = 0; ns < 4; ++ns) {
            int n = nb * 128 + n0w + ns * 16 + (lane & 15);
            bptr[ns] = fcwb + (long)n * D_ + koff;
        }
        for (int kc = 0; kc < D_; kc += 32) {
            short8 a[4], b[4];
            #pragma unroll
            for (int ms = 0; ms < 4; ++ms) a[ms] = *(const short8*)(aptr[ms] + kc);
            #pragma unroll
            for (int ns = 0; ns < 4; ++ns) b[ns] = *(const short8*)(bptr[ns] + kc);
            #pragma unroll
            for (int ms = 0; ms < 4; ++ms)
                #pragma unroll
                for (int ns = 0; ns < 4; ++ns)
                    acc[ms][ns] = __builtin_amdgcn_mfma_f32_16x16x32_bf16(a[ms], b[ns], acc[ms][ns], 0, 0, 0);
        }
    }
    #pragma unroll
    for (int ms = 0; ms < 4; ++ms) {
        #pragma unroll
        for (int r = 0; r < 4; ++r) {
            int rloc = m0w + ms * 16 + ((lane >> 4) << 2) + r;
            int rv = srow[rloc];
            if (rv < 0) continue;                // past end of (b,t) grid: no output row
            bool act = !(rv & (1 << 30));
            int row = rv & 2047;
            int tt = row >> 6, b = row & 63;
            #pragma unroll
            for (int ns = 0; ns < 4; ++ns) {
                int n = nb * 128 + n0w + ns * 16 + (lane & 15);
                out[((long)(b * NT + tt)) * V_ + n] = act ? (acc[ms][ns][r] + fcb[n]) : 0.f;
            }
        }
    }
}

extern "C" void kernel_launch(void* const* d_in, const int* in_sizes, int n_in,
                              void* d_out, int out_size, void* d_ws, size_t ws_size,
                              hipStream_t stream) {
    const float* enc    = (const float*)d_in[0];
    const int*   caplen = (const int*)d_in[1];
    const float* Wih    = (const float*)d_in[2];
    const float* Whh    = (const float*)d_in[3];
    const float* bih    = (const float*)d_in[4];
    const float* bhh    = (const float*)d_in[5];
    const float* fcw    = (const float*)d_in[6];
    const float* fcb    = (const float*)d_in[7];
    float* out = (float*)d_out;

    // workspace carve (~51.5 MB)
    char* ws = (char*)d_ws;
    int* sind    = (int*)ws;                          // 64
    int* declen  = sind + 64;                         // 64
    int* Mact    = declen + 64;                       // 64 (padded)
    int* cntp    = Mact + 64;                         // 64 (own line: barrier counter)
    int* rowlist = cntp + 64;                         // 2048 (uses 1984)
    char* p = (char*)(rowlist + 2048);
    p = (char*)(((size_t)p + 255) & ~(size_t)255);
    float* X      = (float*)p;            p += (size_t)NT * B_ * G4 * 4;   // 16.25 MB
    float* h0     = (float*)p;            p += (size_t)B_ * D_ * 4;        // 128 KB
    float* h1     = (float*)p;            p += (size_t)B_ * D_ * 4;        // (contiguous)
    bf16* hstoreb = (bf16*)p;             p += (size_t)NT * B_ * D_ * 2;   // 2 MB
    bf16* fcwb    = (bf16*)p;             p += (size_t)V_ * D_ * 2;        // 32.8 MB

    float* out_sind = out + (long)B_ * NT * V_;

    k_sort<<<1, 256, 0, stream>>>(caplen, out_sind, sind, declen, Mact, rowlist,
                                  (float4*)h0, cntp);
    k_cvt_fcw<<<4096, 256, 0, stream>>>((const float4*)fcw, (ushort4*)fcwb, (V_ * D_) / 4);
    k_xgemm<<<dim3(NT, G4 / 64), 256, 0, stream>>>(enc, Wih, bih, bhh, sind, X);
    k_lstm<<<NBLK, 512, 0, stream>>>(X, Whh, h0, h1, hstoreb, declen, cntp);
    k_fc<<<dim3(16, 256), 256, 0, stream>>>(hstoreb, fcwb, fcb, rowlist, Mact, out);
}

// Round 5
// 727.203 us; speedup vs baseline: 2.6037x; 1.2075x over previous
//
#include <hip/hip_runtime.h>
#include <hip/hip_bf16.h>
#include <math.h>

#define B_  64
#define T_  32
#define E_  512
#define D_  512
#define V_  32000
#define NT  31            // T-1 decode steps
#define G4  2048          // 4*D
#define NBLK 256          // k_lstm grid: 1 block/CU, all co-resident

typedef __attribute__((ext_vector_type(8))) short short8;
typedef __attribute__((ext_vector_type(4))) float f32x4;
typedef __hip_bfloat16 bf16;

__device__ __forceinline__ float sigmoidf_(float x) { return 1.f / (1.f + expf(-x)); }
// gate-interleaved permutation: col n = d*4+gate  <->  original row gate*512+d
__device__ __forceinline__ int perm_(int n) { return ((n & 3) << 9) + (n >> 2); }

// ---------------- kernel 1: stable descending argsort + init ----------------
__global__ void k_sort(const int* __restrict__ caplen, float* __restrict__ out_sind,
                       int* __restrict__ sind, int* __restrict__ declen,
                       int* __restrict__ Mact, int* __restrict__ rowlist,
                       float4* __restrict__ hz, int* __restrict__ cnt) {
    __shared__ int s_len[B_];
    __shared__ int s_dl[B_];
    __shared__ int s_cnt[NT];
    __shared__ int s_pre[NT + 1];
    int tid = threadIdx.x;
    if (tid < B_) s_len[tid] = caplen[tid];
    __syncthreads();
    if (tid < B_) {
        int len = s_len[tid];
        int rank = 0;
        for (int j = 0; j < B_; ++j) {
            int lj = s_len[j];
            rank += (lj > len) || (lj == len && j < tid);   // stable: ties by index
        }
        sind[rank] = tid;
        declen[rank] = len - 1;
        s_dl[rank] = len - 1;
        out_sind[rank] = (float)tid;
    }
    __syncthreads();
    if (tid < NT) {
        int cntv = 0;
        for (int b = 0; b < B_; ++b) cntv += (tid < s_dl[b]);
        s_cnt[tid] = cntv;
    }
    __syncthreads();
    if (tid == 0) {
        int acc = 0;
        for (int t = 0; t < NT; ++t) { s_pre[t] = acc; acc += s_cnt[t]; }
        s_pre[NT] = acc;
        Mact[0] = acc;
    }
    __syncthreads();
    int Ma = s_pre[NT];
    // full rowlist: [0,Ma) active rows, [Ma,1984) inactive|flag(bit30)
    for (int i = tid; i < NT * B_; i += blockDim.x) {
        int t = i >> 6, b = i & 63;
        bool act = (t < s_dl[b]);          // declen descending -> active iff b < cnt_t
        int pos = act ? (s_pre[t] + b)
                      : (Ma + (t * B_ - s_pre[t]) + (b - s_cnt[t]));
        rowlist[pos] = (t * B_ + b) | (act ? 0 : (1 << 30));
    }
    for (int i = tid; i < 8 * 16; i += blockDim.x) cnt[i] = 0;   // 8 barrier counters
    // zero h0 and h1 (contiguous) as float4
    for (int i = tid; i < (2 * B_ * D_) / 4; i += blockDim.x)
        hz[i] = make_float4(0.f, 0.f, 0.f, 0.f);
}

// ---------------- kernel 2: X = enc_sorted @ Wih[perm].T + bias[perm] (fp32) ----------------
__global__ __launch_bounds__(256) void k_xgemm(
    const float* __restrict__ enc, const float* __restrict__ Wih,
    const float* __restrict__ bih, const float* __restrict__ bhh,
    const int* __restrict__ sind, float* __restrict__ X) {
    __shared__ __align__(16) float sA[16 * 68];
    __shared__ __align__(16) float sB[16 * 68];
    __shared__ int s_sind[B_];
    int tid = threadIdx.x;
    int mt = blockIdx.x;
    int n0 = blockIdx.y * 64;
    if (tid < B_) s_sind[tid] = sind[tid];
    __syncthreads();
    int la = tid >> 2;
    int lk = (tid & 3) << 2;
    int tx = tid & 15, ty = tid >> 4;
    const float* arow = enc + ((long)s_sind[la] * T_ + mt) * E_;
    const float* brow = Wih + (long)perm_(n0 + la) * E_;
    float acc[4][4] = {};
    for (int k0 = 0; k0 < E_; k0 += 16) {
        float4 a4 = *(const float4*)(arow + k0 + lk);
        float4 b4 = *(const float4*)(brow + k0 + lk);
        sA[(lk + 0) * 68 + la] = a4.x; sA[(lk + 1) * 68 + la] = a4.y;
        sA[(lk + 2) * 68 + la] = a4.z; sA[(lk + 3) * 68 + la] = a4.w;
        sB[(lk + 0) * 68 + la] = b4.x; sB[(lk + 1) * 68 + la] = b4.y;
        sB[(lk + 2) * 68 + la] = b4.z; sB[(lk + 3) * 68 + la] = b4.w;
        __syncthreads();
        #pragma unroll
        for (int kk = 0; kk < 16; ++kk) {
            float4 av = *(const float4*)&sA[kk * 68 + (ty << 2)];
            float4 bv = *(const float4*)&sB[kk * 68 + (tx << 2)];
            float a[4] = { av.x, av.y, av.z, av.w };
            float b[4] = { bv.x, bv.y, bv.z, bv.w };
            #pragma unroll
            for (int i = 0; i < 4; ++i)
                #pragma unroll
                for (int j = 0; j < 4; ++j)
                    acc[i][j] = fmaf(a[i], b[j], acc[i][j]);
        }
        __syncthreads();
    }
    #pragma unroll
    for (int i = 0; i < 4; ++i) {
        int b = (ty << 2) + i;
        int row = mt * 64 + b;
        int col0 = n0 + (tx << 2);
        float* xp = X + (long)row * G4 + col0;
        #pragma unroll
        for (int j = 0; j < 4; ++j) {
            int pc = perm_(col0 + j);
            xp[j] = acc[i][j] + bih[pc] + bhh[pc];
        }
    }
}

// ---------------- kernel 3: persistent fused LSTM — all 31 steps, one launch ----------------
// 256 blocks x 512 thr (round-3 proven structure). W in LDS once; c + inactive-h carry in
// registers. Cross-block h via L3 only (relaxed agent atomic stores / sc0sc1 asm loads).
// Grid barrier: round-3's proven RMW-arrive + relaxed-poll, de-contended to 8 counter
// lines (32 arrivals each); lanes 0..7 poll the 8 counters in parallel (one wave).
__global__ __launch_bounds__(512) void k_lstm(
    const float* __restrict__ X, const float* __restrict__ Whh,
    float* __restrict__ hb0, float* __restrict__ hb1,
    bf16* __restrict__ hstoreb, const int* __restrict__ declen,
    int* __restrict__ cnt) {
    __shared__ __align__(16) float sW[8][520];     // [col][k], pad 520: bank-safe
    __shared__ __align__(16) float sp[64 * 72];    // partials [ty][q*8+col], stride 72
    __shared__ float sg[8][65];
    __shared__ int sdl[B_];
    int tid = threadIdx.x;
    int bid = blockIdx.x;
    int n0 = bid * 8;
    if (tid < B_) sdl[tid] = declen[tid];
    {   // stage W once: 8 cols x 512 k (original Whh rows via perm, k contiguous)
        int ci = tid >> 6;            // 0..7
        int kb = (tid & 63) << 3;     // 0,8,...,504
        const float* wr = Whh + (long)perm_(n0 + ci) * D_ + kb;
        float4 w0 = *(const float4*)(wr + 0);
        float4 w1 = *(const float4*)(wr + 4);
        *(float4*)&sW[ci][kb + 0] = w0;
        *(float4*)&sW[ci][kb + 4] = w1;
    }
    __syncthreads();
    int tx = tid & 7;                 // k-chunk lane (also: col in reduce phase)
    int ty = tid >> 3;                // 0..63 batch row
    // c-update ownership: tid<128 -> (b = tid&63, dl = tid>>6), d = bid*2+dl
    int cb = tid & 63, cdl = (tid >> 6) & 1;
    int cd = bid * 2 + cdl;
    int cidx = cb * D_ + cd;
    float creg = 0.f;                 // c state in registers across all steps
    float hreg = 0.f;                 // h carry (covers inactive rows) in registers

    for (int t = 0; t < NT; ++t) {
        const float* hold = (t & 1) ? hb1 : hb0;
        float*       hnew = (t & 1) ? hb0 : hb1;
        // ---- phase A: coherent h loads (L3) + partial dot over this lane's k-chunk
        const float* hrow = hold + ty * D_;
        float4 hv[16];
        #pragma unroll
        for (int kk = 0; kk < 16; ++kk) {
            const float* ap = hrow + ((tx + (kk << 3)) << 2);
            asm volatile("global_load_dwordx4 %0, %1, off sc0 sc1"
                         : "=v"(hv[kk]) : "v"(ap));
        }
        float xv = X[(t * B_ + ty) * G4 + (n0 + tx)];     // L2-warm, used in phase C
        asm volatile("s_waitcnt vmcnt(0)" ::: "memory");
        __builtin_amdgcn_sched_barrier(0);
        float p[8] = {};
        #pragma unroll
        for (int kk = 0; kk < 16; ++kk) {
            int k = (tx + (kk << 3)) << 2;
            #pragma unroll
            for (int j = 0; j < 8; ++j) {
                float4 w4 = *(const float4*)&sW[j][k];   // banks 4*tx..: conflict-free
                p[j] = fmaf(hv[kk].x, w4.x, p[j]);
                p[j] = fmaf(hv[kk].y, w4.y, p[j]);
                p[j] = fmaf(hv[kk].z, w4.z, p[j]);
                p[j] = fmaf(hv[kk].w, w4.w, p[j]);
            }
        }
        float* spp = &sp[ty * 72 + tx * 8];
        *(float4*)(spp + 0) = make_float4(p[0], p[1], p[2], p[3]);
        *(float4*)(spp + 4) = make_float4(p[4], p[5], p[6], p[7]);
        __syncthreads();
        // ---- phase C: reduce 8 partials + bias'd X, activation. thread(tx,ty)->col tx
        {
            float s = xv;
            #pragma unroll
            for (int q = 0; q < 8; ++q) s += sp[ty * 72 + q * 8 + tx];
            sg[tx][ty] = ((tx & 3) == 2) ? tanhf(s) : sigmoidf_(s);
        }
        __syncthreads();
        // ---- phase D: c/h update, h store (coherent, L3)
        if (tid < 128) {
            float gi = sg[cdl * 4 + 0][cb];
            float gf = sg[cdl * 4 + 1][cb];
            float gg = sg[cdl * 4 + 2][cb];
            float go = sg[cdl * 4 + 3][cb];
            float cn = gf * creg + gi * gg;
            float hn = go * tanhf(cn);
            hstoreb[(t * B_ + cb) * D_ + cd] = __float2bfloat16(hn);
            if (t < sdl[cb]) { creg = cn; hreg = hn; }
            __hip_atomic_store((unsigned*)(hnew + cidx), __float_as_uint(hreg),
                               __ATOMIC_RELAXED, __HIP_MEMORY_SCOPE_AGENT);
        }
        if (t == NT - 1) break;                 // no barrier needed after last step
        // ---- grid barrier: 8-way split RMW counters (proven primitives, less contention)
        __syncthreads();                        // drains vmcnt -> h stores visible in L3
        if (tid == 0)
            __hip_atomic_fetch_add(&cnt[(bid & 7) * 16], 1, __ATOMIC_RELAXED,
                                   __HIP_MEMORY_SCOPE_AGENT);
        if (tid < 8) {
            int target = (t + 1) * (NBLK / 8);
            while (__hip_atomic_load(&cnt[tid * 16], __ATOMIC_RELAXED,
                                     __HIP_MEMORY_SCOPE_AGENT) < target)
                __builtin_amdgcn_s_sleep(1);
        }
        __syncthreads();
    }
}

// ---------------- kernel 4: preds = hstore_b @ fcw.T (cvt on the fly) + fc_b ----------------
// 500 blocks x 256 thr; block owns a 64-col strip. fcw fp32 read ONCE, converted to bf16
// into a 64KB XOR-swizzled LDS tile; then loop over all 1984 rows (active: MFMA from LDS,
// inactive: exact-0 store). rowlist via __shfl (no LDS), no __syncthreads in main loop.
__global__ __launch_bounds__(256) void k_fc(
    const bf16* __restrict__ hstoreb, const float* __restrict__ fcw,
    const float* __restrict__ fcb, const int* __restrict__ rowlist,
    const int* __restrict__ Mact, float* __restrict__ out) {
    __shared__ ushort sB[64 * 512];              // 64 KB, XOR-swizzled
    int tid = threadIdx.x, lane = tid & 63, w = tid >> 6;
    int nb = blockIdx.x;                         // 0..499
    int n0 = nb * 64;
    int Ma = Mact[0];
    // ---- stage: fcw[n0..n0+64)[512] fp32 -> bf16 LDS, swizzle phys = log ^ ((c&7)<<4)
    {
        int ko = tid & 63;                       // 16B-chunk index within row (8 bf16)
        int c0 = tid >> 6;                       // 0..3
        for (int c = c0; c < 64; c += 4) {
            const float* src = fcw + (long)(n0 + c) * D_ + ko * 8;
            float4 v0 = *(const float4*)(src + 0);
            float4 v1 = *(const float4*)(src + 4);
            short8 o;
            bf16 b0 = __float2bfloat16(v0.x), b1 = __float2bfloat16(v0.y);
            bf16 b2 = __float2bfloat16(v0.z), b3 = __float2bfloat16(v0.w);
            bf16 b4 = __float2bfloat16(v1.x), b5 = __float2bfloat16(v1.y);
            bf16 b6 = __float2bfloat16(v1.z), b7 = __float2bfloat16(v1.w);
            o[0] = *(short*)&b0; o[1] = *(short*)&b1; o[2] = *(short*)&b2; o[3] = *(short*)&b3;
            o[4] = *(short*)&b4; o[5] = *(short*)&b5; o[6] = *(short*)&b6; o[7] = *(short*)&b7;
            int phys = c * 1024 + ((ko * 16) ^ ((c & 7) << 4));
            *(short8*)((char*)sB + phys) = o;
        }
    }
    __syncthreads();
    // per-lane constants
    int kq = lane >> 4;                          // 0..3
    int sxor = (lane & 7) << 4;
    int kq16 = kq << 4;
    int sBase[4];
    #pragma unroll
    for (int ns = 0; ns < 4; ++ns) sBase[ns] = (ns * 16 + (lane & 15)) * 1024;
    float fq[4];
    #pragma unroll
    for (int ns = 0; ns < 4; ++ns) fq[ns] = fcb[n0 + ns * 16 + (lane & 15)];
    // ---- row-chunk loop: 16 chunks x 128 rows (wave w owns rows w*32..w*32+31)
    for (int rc = 0; rc < 16; ++rc) {
        int base = rc * 128 + w * 32 + (lane & 31);
        int rvec = (base < NT * B_) ? rowlist[base] : -1;
        f32x4 acc[2][4] = {};
        bool domfma = (rc * 128) < Ma;           // actives first in rowlist
        if (domfma) {
            const bf16* ap[2];
            #pragma unroll
            for (int ms = 0; ms < 2; ++ms) {
                int rv = __shfl(rvec, ms * 16 + (lane & 15), 64);
                int ra = (rv < 0) ? 0 : (rv & 2047);
                ap[ms] = hstoreb + (long)ra * D_ + kq * 8;
            }
            #pragma unroll 4
            for (int kci = 0; kci < 16; ++kci) {
                short8 a0 = *(const short8*)(ap[0] + kci * 32);
                short8 a1 = *(const short8*)(ap[1] + kci * 32);
                short8 b[4];
                #pragma unroll
                for (int ns = 0; ns < 4; ++ns)
                    b[ns] = *(const short8*)((const char*)sB + sBase[ns]
                                             + ((kci * 64 + kq16) ^ sxor));
                #pragma unroll
                for (int ns = 0; ns < 4; ++ns) {
                    acc[0][ns] = __builtin_amdgcn_mfma_f32_16x16x32_bf16(a0, b[ns], acc[0][ns], 0, 0, 0);
                    acc[1][ns] = __builtin_amdgcn_mfma_f32_16x16x32_bf16(a1, b[ns], acc[1][ns], 0, 0, 0);
                }
            }
        }
        #pragma unroll
        for (int ms = 0; ms < 2; ++ms) {
            #pragma unroll
            for (int r = 0; r < 4; ++r) {
                int rv = __shfl(rvec, ms * 16 + kq * 4 + r, 64);
                if (rv < 0) continue;            // beyond 1984: no output row
                bool act = !(rv & (1 << 30));
                int row = rv & 2047;
                int tt = row >> 6, b = row & 63;
                float* po = out + ((long)(b * NT + tt)) * V_ + n0 + (lane & 15);
                #pragma unroll
                for (int ns = 0; ns < 4; ++ns)
                    po[ns * 16] = act ? (acc[ms][ns][r] + fq[ns]) : 0.f;
            }
        }
    }
}

extern "C" void kernel_launch(void* const* d_in, const int* in_sizes, int n_in,
                              void* d_out, int out_size, void* d_ws, size_t ws_size,
                              hipStream_t stream) {
    const float* enc    = (const float*)d_in[0];
    const int*   caplen = (const int*)d_in[1];
    const float* Wih    = (const float*)d_in[2];
    const float* Whh    = (const float*)d_in[3];
    const float* bih    = (const float*)d_in[4];
    const float* bhh    = (const float*)d_in[5];
    const float* fcw    = (const float*)d_in[6];
    const float* fcb    = (const float*)d_in[7];
    float* out = (float*)d_out;

    // workspace carve (~18.7 MB)
    char* ws = (char*)d_ws;
    int* sind    = (int*)ws;                          // 64
    int* declen  = sind + 64;                         // 64
    int* Mact    = declen + 64;                       // 64 (padded)
    int* rowlist = Mact + 64;                         // 2048 (uses 1984)
    int* cnt     = rowlist + 2048;                    // 8 counters x 16-int stride
    char* p = (char*)(cnt + 8 * 16);
    p = (char*)(((size_t)p + 255) & ~(size_t)255);
    float* X      = (float*)p;            p += (size_t)NT * B_ * G4 * 4;   // 16.25 MB
    float* h0     = (float*)p;            p += (size_t)B_ * D_ * 4;        // 128 KB
    float* h1     = (float*)p;            p += (size_t)B_ * D_ * 4;        // (contiguous)
    bf16* hstoreb = (bf16*)p;             p += (size_t)NT * B_ * D_ * 2;   // 2 MB

    float* out_sind = out + (long)B_ * NT * V_;

    k_sort<<<1, 256, 0, stream>>>(caplen, out_sind, sind, declen, Mact, rowlist,
                                  (float4*)h0, cnt);
    k_xgemm<<<dim3(NT, G4 / 64), 256, 0, stream>>>(enc, Wih, bih, bhh, sind, X);
    k_lstm<<<NBLK, 512, 0, stream>>>(X, Whh, h0, h1, hstoreb, declen, cnt);
    k_fc<<<dim3(V_ / 64), 256, 0, stream>>>(hstoreb, fcw, fcb, rowlist, Mact, out);
}

// Round 6
// 645.129 us; speedup vs baseline: 2.9349x; 1.1272x over previous
//
#include <hip/hip_runtime.h>
#include <hip/hip_bf16.h>
#include <math.h>

#define B_  64
#define T_  32
#define E_  512
#define D_  512
#define V_  32000
#define NT  31            // T-1 decode steps
#define G4  2048          // 4*D
#define NBLK 256          // k_lstm grid: 1 block/CU, all co-resident

typedef __attribute__((ext_vector_type(8))) short short8;
typedef __attribute__((ext_vector_type(4))) float f32x4;
typedef __hip_bfloat16 bf16;

__device__ __forceinline__ float sigmoidf_(float x) { return 1.f / (1.f + expf(-x)); }
// gate-interleaved permutation: col n = d*4+gate  <->  original row gate*512+d
__device__ __forceinline__ int perm_(int n) { return ((n & 3) << 9) + (n >> 2); }

// ---------------- kernel 1: stable descending argsort + init ----------------
__global__ void k_sort(const int* __restrict__ caplen, float* __restrict__ out_sind,
                       int* __restrict__ sind, int* __restrict__ declen,
                       int* __restrict__ Mact, int* __restrict__ rowlist,
                       float4* __restrict__ hz, int* __restrict__ cnt) {
    __shared__ int s_len[B_];
    __shared__ int s_dl[B_];
    __shared__ int s_cnt[NT];
    __shared__ int s_pre[NT + 1];
    int tid = threadIdx.x;
    if (tid < B_) s_len[tid] = caplen[tid];
    __syncthreads();
    if (tid < B_) {
        int len = s_len[tid];
        int rank = 0;
        for (int j = 0; j < B_; ++j) {
            int lj = s_len[j];
            rank += (lj > len) || (lj == len && j < tid);   // stable: ties by index
        }
        sind[rank] = tid;
        declen[rank] = len - 1;
        s_dl[rank] = len - 1;
        out_sind[rank] = (float)tid;
    }
    __syncthreads();
    if (tid < NT) {
        int cntv = 0;
        for (int b = 0; b < B_; ++b) cntv += (tid < s_dl[b]);
        s_cnt[tid] = cntv;
    }
    __syncthreads();
    if (tid == 0) {
        int acc = 0;
        for (int t = 0; t < NT; ++t) { s_pre[t] = acc; acc += s_cnt[t]; }
        s_pre[NT] = acc;
        Mact[0] = acc;
    }
    __syncthreads();
    int Ma = s_pre[NT];
    // full rowlist: [0,Ma) active rows, [Ma,1984) inactive|flag(bit30)
    for (int i = tid; i < NT * B_; i += blockDim.x) {
        int t = i >> 6, b = i & 63;
        bool act = (t < s_dl[b]);          // declen descending -> active iff b < cnt_t
        int pos = act ? (s_pre[t] + b)
                      : (Ma + (t * B_ - s_pre[t]) + (b - s_cnt[t]));
        rowlist[pos] = (t * B_ + b) | (act ? 0 : (1 << 30));
    }
    for (int i = tid; i < 32 * 16; i += blockDim.x) cnt[i] = 0;   // 32 barrier counters
    // zero h0 and h1 (contiguous) as float4
    for (int i = tid; i < (2 * B_ * D_) / 4; i += blockDim.x)
        hz[i] = make_float4(0.f, 0.f, 0.f, 0.f);
}

// ---------------- kernel 2: X = enc_sorted @ Wih[perm].T + bias[perm] (fp32) ----------------
__global__ __launch_bounds__(256) void k_xgemm(
    const float* __restrict__ enc, const float* __restrict__ Wih,
    const float* __restrict__ bih, const float* __restrict__ bhh,
    const int* __restrict__ sind, float* __restrict__ X) {
    __shared__ __align__(16) float sA[16 * 68];
    __shared__ __align__(16) float sB[16 * 68];
    __shared__ int s_sind[B_];
    int tid = threadIdx.x;
    int mt = blockIdx.x;
    int n0 = blockIdx.y * 64;
    if (tid < B_) s_sind[tid] = sind[tid];
    __syncthreads();
    int la = tid >> 2;
    int lk = (tid & 3) << 2;
    int tx = tid & 15, ty = tid >> 4;
    const float* arow = enc + ((long)s_sind[la] * T_ + mt) * E_;
    const float* brow = Wih + (long)perm_(n0 + la) * E_;
    float acc[4][4] = {};
    for (int k0 = 0; k0 < E_; k0 += 16) {
        float4 a4 = *(const float4*)(arow + k0 + lk);
        float4 b4 = *(const float4*)(brow + k0 + lk);
        sA[(lk + 0) * 68 + la] = a4.x; sA[(lk + 1) * 68 + la] = a4.y;
        sA[(lk + 2) * 68 + la] = a4.z; sA[(lk + 3) * 68 + la] = a4.w;
        sB[(lk + 0) * 68 + la] = b4.x; sB[(lk + 1) * 68 + la] = b4.y;
        sB[(lk + 2) * 68 + la] = b4.z; sB[(lk + 3) * 68 + la] = b4.w;
        __syncthreads();
        #pragma unroll
        for (int kk = 0; kk < 16; ++kk) {
            float4 av = *(const float4*)&sA[kk * 68 + (ty << 2)];
            float4 bv = *(const float4*)&sB[kk * 68 + (tx << 2)];
            float a[4] = { av.x, av.y, av.z, av.w };
            float b[4] = { bv.x, bv.y, bv.z, bv.w };
            #pragma unroll
            for (int i = 0; i < 4; ++i)
                #pragma unroll
                for (int j = 0; j < 4; ++j)
                    acc[i][j] = fmaf(a[i], b[j], acc[i][j]);
        }
        __syncthreads();
    }
    #pragma unroll
    for (int i = 0; i < 4; ++i) {
        int b = (ty << 2) + i;
        int row = mt * 64 + b;
        int col0 = n0 + (tx << 2);
        float* xp = X + (long)row * G4 + col0;
        #pragma unroll
        for (int j = 0; j < 4; ++j) {
            int pc = perm_(col0 + j);
            xp[j] = acc[i][j] + bih[pc] + bhh[pc];
        }
    }
}

// ---------------- kernel 3: persistent fused LSTM — 2D partition ----------------
// 256 blocks = 64 col-groups x 4 row-groups; block owns 16 batch rows x 32 gate-cols
// (= 8 d's x 4 gates -> complete c/h ownership for its (row,d) pairs).
// Thread tile: 2 rows x 8 cols x 32 k (interleaved k-chunks kq*4+kk*64, LDS-conflict-free).
// vs round-5: W ds_read per thread 128->64, h L3 traffic 32->8 MB/step.
// W (64KB) staged to LDS once; c + inactive-h carry in registers.
// Barrier: 32 RMW counters x 8 arrivals (proven primitives).
__global__ __launch_bounds__(512) void k_lstm(
    const float* __restrict__ X, const float* __restrict__ Whh,
    float* __restrict__ hb0, float* __restrict__ hb1,
    bf16* __restrict__ hstoreb, const int* __restrict__ declen,
    int* __restrict__ cnt) {
    __shared__ __align__(16) float sW[32 * 528];   // [col][k], row pad 528
    __shared__ float sp[512 * 17];                 // partials [(row*32+col)][kq]
    __shared__ float sg[32 * 17];                  // gates [col][row]
    int tid = threadIdx.x;
    int bid = blockIdx.x;
    int cg = bid >> 2, rg = bid & 3;
    int n0 = cg * 32;                 // gate-col base
    int d0 = cg * 8;                  // d base
    int r0 = rg * 16;                 // batch-row base
    {   // stage W once: 32 cols x 512 k (original Whh rows via perm, k contiguous)
        int ci = tid & 31;            // col 0..31
        int kseg = tid >> 5;          // 0..15, 32 floats each
        const float* wr = Whh + (long)perm_(n0 + ci) * D_ + kseg * 32;
        float* dst = &sW[ci * 528 + kseg * 32];
        #pragma unroll
        for (int i = 0; i < 8; ++i)
            *(float4*)(dst + i * 4) = *(const float4*)(wr + i * 4);
    }
    // FMA-phase thread mapping
    int kq = tid & 15;                // k-chunk lane
    int rp = (tid >> 4) & 7;          // row-pair 0..7
    int jo = tid >> 7;                // col-octet 0..3
    // phase-C mapping: output (crow, ccol)
    int crow = tid >> 5;              // 0..15
    int ccol = tid & 31;              // 0..31
    // phase-D ownership (tid<128): bl = tid&15, dl = tid>>4 (0..7)
    int bl = tid & 15, dl = (tid >> 4) & 7;
    int gb = r0 + bl;                 // global batch row
    int gd = d0 + dl;                 // global d
    int dlen = declen[gb];            // per-thread (only tid<128 uses)
    float creg = 0.f;                 // c state in registers across all steps
    float hreg = 0.f;                 // h carry (covers inactive rows) in registers
    __syncthreads();

    for (int t = 0; t < NT; ++t) {
        const float* hold = (t & 1) ? hb1 : hb0;
        float*       hnew = (t & 1) ? hb0 : hb1;
        // ---- phase A: coherent h loads (L3): 2 rows x 8 chunks of 4 floats
        float4 hv[2][8];
        #pragma unroll
        for (int kk = 0; kk < 8; ++kk) {
            #pragma unroll
            for (int dr = 0; dr < 2; ++dr) {
                const float* ap = hold + (r0 + rp * 2 + dr) * D_ + kk * 64 + kq * 4;
                asm volatile("global_load_dwordx4 %0, %1, off sc0 sc1"
                             : "=v"(hv[dr][kk]) : "v"(ap));
            }
        }
        float xv = X[(t * B_ + r0 + crow) * G4 + n0 + ccol];   // used in phase C
        asm volatile("s_waitcnt vmcnt(0)" ::: "memory");
        __builtin_amdgcn_sched_barrier(0);
        // ---- phase B: partial dot: 2 rows x 8 cols over this lane's 32 k
        float acc[2][8] = {};
        #pragma unroll
        for (int kk = 0; kk < 8; ++kk) {
            float4 h0 = hv[0][kk];
            float4 h1 = hv[1][kk];
            #pragma unroll
            for (int j = 0; j < 8; ++j) {
                float4 w4 = *(const float4*)&sW[(jo * 8 + j) * 528 + kk * 64 + kq * 4];
                acc[0][j] = fmaf(h0.x, w4.x, acc[0][j]); acc[0][j] = fmaf(h0.y, w4.y, acc[0][j]);
                acc[0][j] = fmaf(h0.z, w4.z, acc[0][j]); acc[0][j] = fmaf(h0.w, w4.w, acc[0][j]);
                acc[1][j] = fmaf(h1.x, w4.x, acc[1][j]); acc[1][j] = fmaf(h1.y, w4.y, acc[1][j]);
                acc[1][j] = fmaf(h1.z, w4.z, acc[1][j]); acc[1][j] = fmaf(h1.w, w4.w, acc[1][j]);
            }
        }
        #pragma unroll
        for (int dr = 0; dr < 2; ++dr)
            #pragma unroll
            for (int j = 0; j < 8; ++j)
                sp[((rp * 2 + dr) * 32 + jo * 8 + j) * 17 + kq] = acc[dr][j];
        __syncthreads();
        // ---- phase C: reduce 16 partials + X, activation -> sg[col][row]
        {
            float s = xv;
            const float* spr = &sp[(crow * 32 + ccol) * 17];
            #pragma unroll
            for (int q = 0; q < 16; ++q) s += spr[q];
            sg[ccol * 17 + crow] = ((ccol & 3) == 2) ? tanhf(s) : sigmoidf_(s);
        }
        __syncthreads();
        // ---- phase D: c/h update, h store (coherent, L3)
        if (tid < 128) {
            float gi = sg[(dl * 4 + 0) * 17 + bl];
            float gf = sg[(dl * 4 + 1) * 17 + bl];
            float gg = sg[(dl * 4 + 2) * 17 + bl];
            float go = sg[(dl * 4 + 3) * 17 + bl];
            float cn = gf * creg + gi * gg;
            float hn = go * tanhf(cn);
            hstoreb[(t * B_ + gb) * D_ + gd] = __float2bfloat16(hn);
            if (t < dlen) { creg = cn; hreg = hn; }
            __hip_atomic_store((unsigned*)(hnew + gb * D_ + gd), __float_as_uint(hreg),
                               __ATOMIC_RELAXED, __HIP_MEMORY_SCOPE_AGENT);
        }
        if (t == NT - 1) break;                 // no barrier needed after last step
        // ---- grid barrier: 32-way split RMW counters + parallel poll
        __syncthreads();                        // drains vmcnt -> h stores visible in L3
        if (tid == 0)
            __hip_atomic_fetch_add(&cnt[(bid & 31) * 16], 1, __ATOMIC_RELAXED,
                                   __HIP_MEMORY_SCOPE_AGENT);
        if (tid < 32) {
            int target = (t + 1) * (NBLK / 32);
            while (__hip_atomic_load(&cnt[tid * 16], __ATOMIC_RELAXED,
                                     __HIP_MEMORY_SCOPE_AGENT) < target)
                __builtin_amdgcn_s_sleep(1);
        }
        __syncthreads();
    }
}

// ---------------- kernel 4: preds = hstore_b @ fcw.T (cvt on the fly) + fc_b ----------------
// 500 blocks x 512 thr (8 waves; 2 blocks/CU -> 4 waves/SIMD for latency hiding).
// Block owns a 64-col strip; fcw fp32 read ONCE -> bf16 into 64KB XOR-swizzled LDS tile;
// loop over all 1984 rows (active: MFMA from LDS, inactive: exact-0 store).
__global__ __launch_bounds__(512) void k_fc(
    const bf16* __restrict__ hstoreb, const float* __restrict__ fcw,
    const float* __restrict__ fcb, const int* __restrict__ rowlist,
    const int* __restrict__ Mact, float* __restrict__ out) {
    __shared__ ushort sB[64 * 512];              // 64 KB, XOR-swizzled
    int tid = threadIdx.x, lane = tid & 63, w = tid >> 6;   // 8 waves
    int nb = blockIdx.x;                         // 0..499
    int n0 = nb * 64;
    int Ma = Mact[0];
    // ---- stage: fcw[n0..n0+64)[512] fp32 -> bf16 LDS, swizzle phys = log ^ ((c&7)<<4)
    {
        int ko = lane;                           // 16B-chunk index within row (8 bf16)
        for (int c = w; c < 64; c += 8) {
            const float* src = fcw + (long)(n0 + c) * D_ + ko * 8;
            float4 v0 = *(const float4*)(src + 0);
            float4 v1 = *(const float4*)(src + 4);
            short8 o;
            bf16 b0 = __float2bfloat16(v0.x), b1 = __float2bfloat16(v0.y);
            bf16 b2 = __float2bfloat16(v0.z), b3 = __float2bfloat16(v0.w);
            bf16 b4 = __float2bfloat16(v1.x), b5 = __float2bfloat16(v1.y);
            bf16 b6 = __float2bfloat16(v1.z), b7 = __float2bfloat16(v1.w);
            o[0] = *(short*)&b0; o[1] = *(short*)&b1; o[2] = *(short*)&b2; o[3] = *(short*)&b3;
            o[4] = *(short*)&b4; o[5] = *(short*)&b5; o[6] = *(short*)&b6; o[7] = *(short*)&b7;
            int phys = c * 1024 + ((ko * 16) ^ ((c & 7) << 4));
            *(short8*)((char*)sB + phys) = o;
        }
    }
    __syncthreads();
    // per-lane constants
    int kq = lane >> 4;                          // 0..3
    int sxor = (lane & 7) << 4;
    int kq16 = kq << 4;
    int sBase[4];
    #pragma unroll
    for (int ns = 0; ns < 4; ++ns) sBase[ns] = (ns * 16 + (lane & 15)) * 1024;
    float fq[4];
    #pragma unroll
    for (int ns = 0; ns < 4; ++ns) fq[ns] = fcb[n0 + ns * 16 + (lane & 15)];
    // ---- row-chunk loop: 16 chunks x 128 rows (wave w owns 16 rows per chunk)
    for (int rc = 0; rc < 16; ++rc) {
        int base = rc * 128 + w * 16;
        int ridx = base + (lane & 15);
        int rvec = (ridx < NT * B_) ? rowlist[ridx] : -1;
        f32x4 acc[4] = {};
        bool domfma = (base < Ma);               // actives first in rowlist
        if (domfma) {
            const bf16* ap = hstoreb + (long)((rvec < 0) ? 0 : (rvec & 2047)) * D_ + kq * 8;
            #pragma unroll 4
            for (int kci = 0; kci < 16; ++kci) {
                short8 a0 = *(const short8*)(ap + kci * 32);
                short8 b[4];
                #pragma unroll
                for (int ns = 0; ns < 4; ++ns)
                    b[ns] = *(const short8*)((const char*)sB + sBase[ns]
                                             + ((kci * 64 + kq16) ^ sxor));
                #pragma unroll
                for (int ns = 0; ns < 4; ++ns)
                    acc[ns] = __builtin_amdgcn_mfma_f32_16x16x32_bf16(a0, b[ns], acc[ns], 0, 0, 0);
            }
        }
        #pragma unroll
        for (int r = 0; r < 4; ++r) {
            int rv = __shfl(rvec, kq * 4 + r, 16);
            if (rv < 0) continue;                // beyond 1984: no output row
            bool act = !(rv & (1 << 30));
            int row = rv & 2047;
            int tt = row >> 6, b = row & 63;
            float* po = out + ((long)(b * NT + tt)) * V_ + n0 + (lane & 15);
            #pragma unroll
            for (int ns = 0; ns < 4; ++ns)
                po[ns * 16] = act ? (acc[ns][r] + fq[ns]) : 0.f;
        }
    }
}

extern "C" void kernel_launch(void* const* d_in, const int* in_sizes, int n_in,
                              void* d_out, int out_size, void* d_ws, size_t ws_size,
                              hipStream_t stream) {
    const float* enc    = (const float*)d_in[0];
    const int*   caplen = (const int*)d_in[1];
    const float* Wih    = (const float*)d_in[2];
    const float* Whh    = (const float*)d_in[3];
    const float* bih    = (const float*)d_in[4];
    const float* bhh    = (const float*)d_in[5];
    const float* fcw    = (const float*)d_in[6];
    const float* fcb    = (const float*)d_in[7];
    float* out = (float*)d_out;

    // workspace carve (~18.7 MB)
    char* ws = (char*)d_ws;
    int* sind    = (int*)ws;                          // 64
    int* declen  = sind + 64;                         // 64
    int* Mact    = declen + 64;                       // 64 (padded)
    int* rowlist = Mact + 64;                         // 2048 (uses 1984)
    int* cnt     = rowlist + 2048;                    // 32 counters x 16-int stride
    char* p = (char*)(cnt + 32 * 16);
    p = (char*)(((size_t)p + 255) & ~(size_t)255);
    float* X      = (float*)p;            p += (size_t)NT * B_ * G4 * 4;   // 16.25 MB
    float* h0     = (float*)p;            p += (size_t)B_ * D_ * 4;        // 128 KB
    float* h1     = (float*)p;            p += (size_t)B_ * D_ * 4;        // (contiguous)
    bf16* hstoreb = (bf16*)p;             p += (size_t)NT * B_ * D_ * 2;   // 2 MB

    float* out_sind = out + (long)B_ * NT * V_;

    k_sort<<<1, 256, 0, stream>>>(caplen, out_sind, sind, declen, Mact, rowlist,
                                  (float4*)h0, cnt);
    k_xgemm<<<dim3(NT, G4 / 64), 256, 0, stream>>>(enc, Wih, bih, bhh, sind, X);
    k_lstm<<<NBLK, 512, 0, stream>>>(X, Whh, h0, h1, hstoreb, declen, cnt);
    k_fc<<<dim3(V_ / 64), 512, 0, stream>>>(hstoreb, fcw, fcb, rowlist, Mact, out);
}